// Round 15
// baseline (647.064 us; speedup 1.0000x reference)
//
#include <hip/hip_runtime.h>
#include <hip/hip_bf16.h>
#include <hip/hip_fp16.h>

typedef __hip_bfloat16 bf16;
typedef __attribute__((ext_vector_type(8))) short short8;
typedef __attribute__((ext_vector_type(8))) _Float16 half8;
typedef __attribute__((ext_vector_type(4))) float f32x4;

#define N_TOK 65536
#define C_DIM 192
#define SCALE 0.17677669529663687f

__device__ __forceinline__ float b2f(bf16 v) { return __bfloat162float(v); }
__device__ __forceinline__ bf16 f2b(float v) { return __float2bfloat16(v); }
__device__ __forceinline__ float ldA(const void* p, size_t i, int f32) {
  return f32 ? ((const float*)p)[i] : b2f(((const bf16*)p)[i]);
}
__device__ __forceinline__ float s2f(short s) { union { short s; bf16 b; } u; u.s = s; return b2f(u.b); }

// fast GELU (tanh form): s * sigmoid(1.5957691*s + 0.0713548*s^3); max err ~1e-3.
__device__ __forceinline__ float gelu_f(float s) {
  float t = s * s;
  float b = s * (-1.59576912f - 0.0713548162f * t);
  float e = __expf(b);
  return s / (1.f + e);
}

// ---------------- dtype detector (silent) ----------------
__global__ void detect_kernel(const unsigned short* __restrict__ xh, int* __restrict__ flag) {
  if (threadIdx.x == 0) {
    int crazy = 0;
    for (int i = 0; i < 256; ++i) {
      int e = (xh[i] >> 7) & 0xFF;
      if (e >= 0xF0 || (e >= 1 && e <= 0x60)) ++crazy;
    }
    *flag = (crazy >= 16) ? 1 : 0;
  }
}

// ---------------- prep: transposes + casts (all elementwise, exact 256-multiples) ------
__global__ __launch_bounds__(256) void prep_xpose_kernel(
    const void* __restrict__ qkv_w, bf16* __restrict__ QKVT,
    const void* __restrict__ proj_w, bf16* __restrict__ PROJT,
    const void* __restrict__ dw_w, _Float16* __restrict__ DWT,
    const void* __restrict__ fc1_A, bf16* __restrict__ FC1AB,
    const void* __restrict__ fc1_Bw, bf16* __restrict__ FC1BWT,
    const void* __restrict__ fc2_A, bf16* __restrict__ FC2AB,
    const void* __restrict__ fc2_Bw, bf16* __restrict__ FC2BWT,
    const int* __restrict__ flag) {
  int f32 = *flag;
  int b = blockIdx.x;
  if (b < 432) {
    int idx = b * 256 + threadIdx.x;
    int n = idx / 192, k = idx - n * 192;
    QKVT[idx] = f2b(ldA(qkv_w, (size_t)k * 576 + n, f32));
  } else if (b < 576) {
    int idx = (b - 432) * 256 + threadIdx.x;
    int n = idx / 192, k = idx - n * 192;
    PROJT[idx] = f2b(ldA(proj_w, (size_t)k * 192 + n, f32));
  } else if (b < 657) {
    int idx = (b - 576) * 256 + threadIdx.x;       // 27*768 exact
    int tap = idx / 768, c = idx - tap * 768;
    DWT[idx] = (_Float16)ldA(dw_w, (size_t)c * 27 + tap, f32);
  } else if (b < 945) {
    int idx = (b - 657) * 256 + threadIdx.x;       // 73728 exact
    FC1AB[idx] = f2b(ldA(fc1_A, idx, f32));
  } else if (b < 2097) {
    int idx = (b - 945) * 256 + threadIdx.x;       // 294912 exact
    int n = idx / 384, r = idx - n * 384;
    FC1BWT[idx] = f2b(ldA(fc1_Bw, (size_t)r * 768 + n, f32));
  } else if (b < 2385) {
    int idx = (b - 2097) * 256 + threadIdx.x;      // 73728 exact
    FC2AB[idx] = f2b(ldA(fc2_A, idx, f32));
  } else {
    int idx = (b - 2385) * 256 + threadIdx.x;      // 18432 exact
    int n = idx / 96, r = idx - n * 96;
    FC2BWT[idx] = f2b(ldA(fc2_Bw, (size_t)r * 192 + n, f32));
  }
}

// ---------------- LayerNorm ----------------
__global__ __launch_bounds__(256) void ln_kernel(const void* __restrict__ x,
    const void* __restrict__ g, const void* __restrict__ b, bf16* __restrict__ out,
    int windowize, int xIsBf16Fixed, const int* __restrict__ flag) {
  int wf32 = *flag;
  int f32 = xIsBf16Fixed ? 0 : wf32;
  int token = blockIdx.x * 4 + (threadIdx.x >> 6);
  int lane = threadIdx.x & 63;
  size_t base = (size_t)token * C_DIM;
  float v0 = ldA(x, base + lane, f32);
  float v1 = ldA(x, base + lane + 64, f32);
  float v2 = ldA(x, base + lane + 128, f32);
  float s = v0 + v1 + v2;
  float s2 = v0 * v0 + v1 * v1 + v2 * v2;
  #pragma unroll
  for (int o = 32; o > 0; o >>= 1) { s += __shfl_xor(s, o, 64); s2 += __shfl_xor(s2, o, 64); }
  float mu = s * (1.f / 192.f);
  float var = s2 * (1.f / 192.f) - mu * mu;
  float rstd = rsqrtf(var + 1e-5f);
  int row = token;
  if (windowize) {
    int d = token >> 12, h = (token >> 6) & 63, w = token & 63;
    int win = ((d >> 2) << 6) + ((h >> 3) << 3) + (w >> 3);
    int t = ((d & 3) << 6) + ((h & 7) << 3) + (w & 7);
    row = win * 256 + t;
  }
  bf16* po = out + (size_t)row * C_DIM;
  po[lane]       = f2b((v0 - mu) * rstd * ldA(g, lane, wf32)       + ldA(b, lane, wf32));
  po[lane + 64]  = f2b((v1 - mu) * rstd * ldA(g, lane + 64, wf32)  + ldA(b, lane + 64, wf32));
  po[lane + 128] = f2b((v2 - mu) * rstd * ldA(g, lane + 128, wf32) + ldA(b, lane + 128, wf32));
}

// ---------------- MFMA GEMM, BK=96, global_load_lds staging (linear LDS) ----------------
// Template F16: 0 = bf16 MFMA inputs, 1 = f16 MFMA inputs.
// mode 0: bf16 store (+bias); 1: adaptive + residual; 3: window->natural + res;
// 4: transposed bf16 store; 5: f16 store (+bias); 6: transposed f16 store.
// Modes 0/5 (pure-store, exact grids) use an LDS-staged vectorized epilogue.
template<int F16>
__global__ __launch_bounds__(256) void mfma_gemm(const bf16* __restrict__ A,
    const bf16* __restrict__ BT, const void* __restrict__ bias,
    const void* __restrict__ res, void* __restrict__ out,
    int Nc, int K, int ldk, int mode, int Mrows, const int* __restrict__ flag) {
  int f32 = *flag;
  __shared__ short As[128 * 96];
  __shared__ short Bs[64 * 96];
  int tid = threadIdx.x;
  int wave = tid >> 6, lane = tid & 63;
  int wm = wave >> 1, wn = wave & 1;
  int lr = lane & 15, quad = lane >> 4;
  int rowBase, colBase;
  if (gridDim.y >= 8) {
    int ncb = gridDim.x;
    int flat = blockIdx.x + ncb * blockIdx.y;
    int group = flat / (8 * ncb);
    int r = flat - group * 8 * ncb;
    rowBase = (group * 8 + (r & 7)) * 128;
    colBase = (r >> 3) * 64;
  } else {
    rowBase = blockIdx.y * 128;
    colBase = blockIdx.x * 64;
  }
  f32x4 acc[4][2];
  #pragma unroll
  for (int i = 0; i < 4; ++i)
    #pragma unroll
    for (int j = 0; j < 2; ++j) acc[i][j] = f32x4{0.f, 0.f, 0.f, 0.f};

  const bf16* arow = A + (size_t)rowBase * K;
  const bf16* brow = BT + (size_t)colBase * ldk;

  for (int k0 = 0; k0 < K; k0 += 96) {
    #pragma unroll
    for (int it = 0; it < 6; ++it) {
      int u = tid + it * 256;
      int row = u / 12, kc = (u - row * 12) * 8;
      __builtin_amdgcn_global_load_lds(
          (const __attribute__((address_space(1))) void*)(arow + (size_t)row * K + k0 + kc),
          (__attribute__((address_space(3))) void*)&As[u * 8], 16, 0, 0);
    }
    #pragma unroll
    for (int it = 0; it < 3; ++it) {
      int u = tid + it * 256;
      int n = u / 12, kc = (u - n * 12) * 8;
      __builtin_amdgcn_global_load_lds(
          (const __attribute__((address_space(1))) void*)(brow + (size_t)n * ldk + k0 + kc),
          (__attribute__((address_space(3))) void*)&Bs[u * 8], 16, 0, 0);
    }
    __syncthreads();
    #pragma unroll
    for (int kk = 0; kk < 3; ++kk) {
      short8 af[4], bf[2];
      #pragma unroll
      for (int i = 0; i < 4; ++i)
        af[i] = *(const short8*)&As[(wm * 64 + i * 16 + lr) * 96 + kk * 32 + quad * 8];
      #pragma unroll
      for (int j = 0; j < 2; ++j)
        bf[j] = *(const short8*)&Bs[(wn * 32 + j * 16 + lr) * 96 + kk * 32 + quad * 8];
      #pragma unroll
      for (int i = 0; i < 4; ++i)
        #pragma unroll
        for (int j = 0; j < 2; ++j) {
          if constexpr (F16) {
            union { short8 s; half8 h; } ua, ub;
            ua.s = af[i]; ub.s = bf[j];
            acc[i][j] = __builtin_amdgcn_mfma_f32_16x16x32_f16(ua.h, ub.h, acc[i][j], 0, 0, 0);
          } else {
            acc[i][j] = __builtin_amdgcn_mfma_f32_16x16x32_bf16(af[i], bf[j], acc[i][j], 0, 0, 0);
          }
        }
    }
    __syncthreads();
  }

  if (mode == 0 || mode == 5) {
    // ---- vectorized epilogue: stage C tile in LDS, then 16B coalesced stores ----
    short* Cs = As;                         // 128 x 72 shorts = 18.4 KB, free now
    #pragma unroll
    for (int i = 0; i < 4; ++i) {
      #pragma unroll
      for (int j = 0; j < 2; ++j) {
        #pragma unroll
        for (int r4 = 0; r4 < 4; ++r4) {
          int row = wm * 64 + i * 16 + quad * 4 + r4;
          int c = wn * 32 + j * 16 + lr;
          float v = acc[i][j][r4];
          if (bias) v += ldA(bias, colBase + c, f32);
          short bits;
          if (mode == 5) { union { _Float16 h; short s; } u2; u2.h = (_Float16)v; bits = u2.s; }
          else           { union { bf16 b; short s; } u2; u2.b = f2b(v); bits = u2.s; }
          Cs[row * 72 + c] = bits;
        }
      }
    }
    __syncthreads();
    int row = tid >> 1, half = tid & 1;     // 2 threads/row, 32 shorts each
    size_t gbase = (size_t)(rowBase + row) * Nc + colBase + half * 32;
    #pragma unroll
    for (int ch = 0; ch < 4; ++ch) {
      short8 vv = *(const short8*)&Cs[row * 72 + half * 32 + ch * 8];
      if (mode == 5) *(short8*)((_Float16*)out + gbase + ch * 8) = vv;
      else           *(short8*)((bf16*)out + gbase + ch * 8) = vv;
    }
    return;
  }

  #pragma unroll
  for (int i = 0; i < 4; ++i) {
    #pragma unroll
    for (int j = 0; j < 2; ++j) {
      #pragma unroll
      for (int r4 = 0; r4 < 4; ++r4) {
        int row = rowBase + wm * 64 + i * 16 + quad * 4 + r4;
        int c = colBase + wn * 32 + j * 16 + lr;
        if (c >= Nc || row >= Mrows) continue;
        float v = acc[i][j][r4];
        if (bias) v += ldA(bias, c, f32);
        if (mode == 1) {
          float o = b2f(((const bf16*)res)[(size_t)row * Nc + c]) + v;
          if (f32) ((float*)out)[(size_t)row * Nc + c] = o;
          else     ((bf16*)out)[(size_t)row * Nc + c] = f2b(o);
        } else if (mode == 4) {
          ((bf16*)out)[(size_t)c * Mrows + row] = f2b(v);
        } else if (mode == 6) {
          ((_Float16*)out)[(size_t)c * Mrows + row] = (_Float16)v;
        } else {  // mode 3: proj + residual, window -> natural
          int win = row >> 8, t = row & 255;
          int d = ((win >> 6) << 2) + (t >> 6);
          int h = (((win >> 3) & 7) << 3) + ((t >> 3) & 7);
          int w = ((win & 7) << 3) + (t & 7);
          int n = (d << 12) + (h << 6) + w;
          ((bf16*)out)[(size_t)n * C_DIM + c] = f2b(ldA(res, (size_t)n * C_DIM + c, f32) + v);
        }
      }
    }
  }
}

// ---------------- MFMA attention from row-major QKV (win-token, 576) ----------------
__global__ __launch_bounds__(256) void attn_mfma_kernel(const bf16* __restrict__ qkvr,
    const void* __restrict__ rel_bias, bf16* __restrict__ out,
    const int* __restrict__ flag) {
  int f32 = *flag;
  __shared__ bf16 sK[256 * 40];
  __shared__ bf16 sVT[32 * 264];
  __shared__ bf16 sP[4][64 * 40];
  __shared__ float sb[1575];
  __shared__ int  sgb[256];
  int head = blockIdx.x, win = blockIdx.y;
  const bf16* base = qkvr + (size_t)win * 256 * 576;
  int qoff = head * 32, koff = 192 + head * 32, voff = 384 + head * 32;
  int tid = threadIdx.x;
  int wave = tid >> 6, lane = tid & 63;
  int lr = lane & 15, quad = lane >> 4;

  #pragma unroll
  for (int it = 0; it < 4; ++it) {
    int idx = tid + it * 256;              // 0..1023
    int tok = idx >> 2, kc = (idx & 3) * 8;
    uint4 v = *(const uint4*)(base + (size_t)tok * 576 + koff + kc);
    *(uint4*)&sK[tok * 40 + kc] = v;
  }
  for (int idx = tid; idx < 8192; idx += 256) {
    int tok = idx >> 5, hd = idx & 31;
    sVT[hd * 264 + tok] = base[(size_t)tok * 576 + voff + hd];
  }
  for (int idx = tid; idx < 1575; idx += 256) sb[idx] = ldA(rel_bias, (size_t)idx * 6 + head, f32);
  {
    int t = tid & 255;
    int d = ((win >> 6) << 2) + (t >> 6);
    int h = (((win >> 3) & 7) << 3) + ((t >> 3) & 7);
    int w = ((win & 7) << 3) + (t & 7);
    int d2 = (d + 2) & 15, h2 = (h + 4) & 63, w2 = (w + 4) & 63;
    int g = ((d2 >> 2) << 6) + ((h2 >> 3) << 3) + (w2 >> 3);
    int td = t >> 6, th = (t >> 3) & 7, tw = t & 7;
    int bse = (td * 15 + th) * 15 + tw;
    sgb[t] = (g << 12) | bse;
  }
  __syncthreads();

  int wm = wave * 64;
  short8 aq[4];
  #pragma unroll
  for (int i = 0; i < 4; ++i)
    aq[i] = *(const short8*)(base + (size_t)(wm + i * 16 + lr) * 576 + qoff + quad * 8);
  int rinfo[16];
  #pragma unroll
  for (int i = 0; i < 4; ++i)
    #pragma unroll
    for (int r = 0; r < 4; ++r)
      rinfo[i * 4 + r] = sgb[wm + i * 16 + quad * 4 + r];

  f32x4 acc_o[4][2], acc_l[4];
  #pragma unroll
  for (int i = 0; i < 4; ++i) {
    acc_l[i] = f32x4{0.f, 0.f, 0.f, 0.f};
    #pragma unroll
    for (int j = 0; j < 2; ++j) acc_o[i][j] = f32x4{0.f, 0.f, 0.f, 0.f};
  }
  short8 bones;
  #pragma unroll
  for (int j = 0; j < 8; ++j) bones[j] = (lr == 0) ? (short)0x3F80 : (short)0;

  for (int c = 0; c < 8; ++c) {
    short8 bk[2];
    #pragma unroll
    for (int jt = 0; jt < 2; ++jt)
      bk[jt] = *(const short8*)&sK[(c * 32 + jt * 16 + lr) * 40 + quad * 8];
    f32x4 s[4][2];
    #pragma unroll
    for (int i = 0; i < 4; ++i)
      #pragma unroll
      for (int jt = 0; jt < 2; ++jt) {
        s[i][jt] = f32x4{0.f, 0.f, 0.f, 0.f};
        s[i][jt] = __builtin_amdgcn_mfma_f32_16x16x32_bf16(aq[i], bk[jt], s[i][jt], 0, 0, 0);
      }
    int cinfo[2];
    #pragma unroll
    for (int jt = 0; jt < 2; ++jt) cinfo[jt] = sgb[c * 32 + jt * 16 + lr];
    #pragma unroll
    for (int i = 0; i < 4; ++i)
      #pragma unroll
      for (int jt = 0; jt < 2; ++jt)
        #pragma unroll
        for (int r = 0; r < 4; ++r) {
          int ri = rinfo[i * 4 + r], ci = cinfo[jt];
          float sc = s[i][jt][r] * SCALE + sb[(ri & 0xFFF) - (ci & 0xFFF) + 787];
          float p = ((ri >> 12) == (ci >> 12)) ? __expf(sc) : 0.f;
          sP[wave][(i * 16 + quad * 4 + r) * 40 + jt * 16 + lr] = f2b(p);
        }
    short8 ap[4];
    #pragma unroll
    for (int i = 0; i < 4; ++i)
      ap[i] = *(const short8*)&sP[wave][(i * 16 + lr) * 40 + quad * 8];
    short8 bv[2];
    #pragma unroll
    for (int jh = 0; jh < 2; ++jh)
      bv[jh] = *(const short8*)&sVT[(jh * 16 + lr) * 264 + c * 32 + quad * 8];
    #pragma unroll
    for (int i = 0; i < 4; ++i) {
      #pragma unroll
      for (int jh = 0; jh < 2; ++jh)
        acc_o[i][jh] = __builtin_amdgcn_mfma_f32_16x16x32_bf16(ap[i], bv[jh], acc_o[i][jh], 0, 0, 0);
      acc_l[i] = __builtin_amdgcn_mfma_f32_16x16x32_bf16(ap[i], bones, acc_l[i], 0, 0, 0);
    }
  }
  #pragma unroll
  for (int i = 0; i < 4; ++i) {
    #pragma unroll
    for (int r = 0; r < 4; ++r) {
      float l = __shfl(acc_l[i][r], lane & 48, 64);
      float inv = 1.f / l;
      int t = wm + i * 16 + quad * 4 + r;
      bf16* po = out + (size_t)(win * 256 + t) * C_DIM + head * 32;
      po[lr]      = f2b(acc_o[i][0][r] * inv);
      po[16 + lr] = f2b(acc_o[i][1][r] * inv);
    }
  }
}

// ---------------- Depthwise conv + GELU, packed f16, 8 ch x 4 d-tokens (sliding d) ----
// Over-fetch fix (thread-mapping, not block-order): thread owns 4 consecutive
// d-positions; the 3-tap d-window slides in registers (xf[6]) so the d-re-fetch
// that previously missed L2 (d+-1 readers were 1024 quads away -> 3.6x FETCH)
// now happens in-thread. Unit order dq->h->w + XCD chunking keeps w-halo window
// (~3.1 MB) and h-halo inside the 4 MB per-XCD L2. Load/store counts and
// coalescing identical to the w-sliding version (96 consecutive threads cover
// one token's 768 channels in both layouts).
__global__ __launch_bounds__(256, 8) void dwconv_f16_kernel(const _Float16* __restrict__ in,
    const _Float16* __restrict__ wT, const void* __restrict__ wb, _Float16* __restrict__ out,
    const int* __restrict__ flag) {
  int f32 = *flag;
  int vb = (blockIdx.x & 7) * (gridDim.x >> 3) + (blockIdx.x >> 3);  // XCD-chunked
  int idx = vb * 256 + threadIdx.x;           // 16384 units * 96 cgroups
  int u = idx / 96, g = idx - u * 96;
  int c0 = g * 8;
  int dq = u & 3, h = (u >> 2) & 63, w = u >> 8;   // dq fastest, then h, then w
  int d0 = dq << 2;
  const _Float16* inb = in + c0;
  half8 acc[4];
  #pragma unroll
  for (int t = 0; t < 4; ++t)
    #pragma unroll
    for (int e = 0; e < 8; ++e) acc[t][e] = (_Float16)0.f;
  #pragma unroll
  for (int kh = 0; kh < 3; ++kh) {
    int hh = h + kh - 1;
    if ((unsigned)hh >= 64u) continue;
    #pragma unroll
    for (int kw = 0; kw < 3; ++kw) {
      int ww = w + kw - 1;
      if ((unsigned)ww >= 64u) continue;
      int colbase = (hh << 6) + ww;
      half8 xf[6];
      #pragma unroll
      for (int j = 0; j < 6; ++j) {
        int dd = d0 + j - 1;
        if ((unsigned)dd < 16u) {
          xf[j] = *(const half8*)(inb + (size_t)((dd << 12) + colbase) * 768);
        } else {
          #pragma unroll
          for (int e = 0; e < 8; ++e) xf[j][e] = (_Float16)0.f;
        }
      }
      #pragma unroll
      for (int kd = 0; kd < 3; ++kd) {
        half8 wv = *(const half8*)(wT + (kd * 9 + kh * 3 + kw) * 768 + c0);
        #pragma unroll
        for (int t = 0; t < 4; ++t)
          acc[t] += xf[t + kd] * wv;        // v_pk_fma_f16 x4
      }
    }
  }
  float biasf[8];
  #pragma unroll
  for (int e = 0; e < 8; ++e) biasf[e] = ldA(wb, c0 + e, f32);
  #pragma unroll
  for (int t = 0; t < 4; ++t) {
    half8 po;
    #pragma unroll
    for (int e = 0; e < 8; ++e) {
      float s = (float)acc[t][e] + biasf[e];
      po[e] = (_Float16)gelu_f(s);
    }
    *(half8*)(out + (size_t)(((d0 + t) << 12) + (h << 6) + w) * 768 + c0) = po;
  }
}

extern "C" void kernel_launch(void* const* d_in, const int* in_sizes, int n_in,
                              void* d_out, int out_size, void* d_ws, size_t ws_size,
                              hipStream_t stream) {
  const void* x      = d_in[0];
  const void* n1g    = d_in[1];
  const void* n1b    = d_in[2];
  const void* qkv_w  = d_in[3];
  const void* qkv_b  = d_in[4];
  const void* relb   = d_in[5];
  const void* proj_w = d_in[6];
  const void* proj_b = d_in[7];
  const void* n2g    = d_in[8];
  const void* n2b    = d_in[9];
  const void* fc1_A  = d_in[10];
  const void* fc1_Bw = d_in[11];
  const void* fc1_Bb = d_in[12];
  const void* dw_w   = d_in[13];
  const void* dw_b   = d_in[14];
  const void* fc2_A  = d_in[15];
  const void* fc2_Bw = d_in[16];
  const void* fc2_Bb = d_in[17];

  // ws layout (MiB), 256 total.
  char* ws = (char*)d_ws;
  bf16* SCR  = (bf16*)d_out;                         // H1 / ATT / H2 scratch
  bf16* X1   = (bf16*)(ws);
  bf16* QKVR = (bf16*)(ws + (size_t)24 * 1048576);
  _Float16* F2 = (_Float16*)(ws + (size_t)24 * 1048576);
  _Float16* F1 = (_Float16*)(ws + (size_t)120 * 1048576);
  bf16* QKVT   = (bf16*)(ws + (size_t)228 * 1048576); // (576,192)
  bf16* PROJT  = (bf16*)(ws + (size_t)229 * 1048576); // (192,192)
  _Float16* DWT = (_Float16*)(ws + (size_t)230 * 1048576); // (27,768) f16
  bf16* W1T    = (bf16*)(ws + (size_t)231 * 1048576); // (768,192) bf16
  _Float16* W2T = (_Float16*)(ws + (size_t)232 * 1048576); // (192,768) f16
  bf16* FC1AB  = (bf16*)(ws + (size_t)233 * 1048576); // (192,384) bf16 cast
  bf16* FC1BWT = (bf16*)(ws + (size_t)234 * 1048576); // (768,384) transpose
  bf16* FC2AB  = (bf16*)(ws + (size_t)236 * 1048576); // (768,96) bf16 cast
  bf16* FC2BWT = (bf16*)(ws + (size_t)237 * 1048576); // (192,96) transpose
  int* FLAG    = (int*)(ws + (size_t)255 * 1048576);

  // 0. dtype detect + weight prep
  detect_kernel<<<1, 64, 0, stream>>>((const unsigned short*)x, FLAG);
  prep_xpose_kernel<<<2457, 256, 0, stream>>>(qkv_w, QKVT, proj_w, PROJT, dw_w, DWT,
                                              fc1_A, FC1AB, fc1_Bw, FC1BWT,
                                              fc2_A, FC2AB, fc2_Bw, FC2BWT, FLAG);
  // 0b. W1 = fc1_A @ fc1_Bw (192x768, K=384) -> W1T bf16, mode 4 transposed store
  mfma_gemm<0><<<dim3(12, 2), 256, 0, stream>>>(FC1AB, FC1BWT, nullptr, nullptr, W1T,
                                                768, 384, 384, 4, 192, FLAG);
  // 0c. W2 = fc2_A @ fc2_Bw (768x192, K=96) -> W2T f16, mode 6
  mfma_gemm<0><<<dim3(3, 6), 256, 0, stream>>>(FC2AB, FC2BWT, nullptr, nullptr, W2T,
                                               192, 96, 96, 6, 768, FLAG);
  // 1. LN1 + window gather -> SCR (H1)
  ln_kernel<<<N_TOK / 4, 256, 0, stream>>>(x, n1g, n1b, SCR, 1, 0, FLAG);
  // 2. QKV gemm -> row-major QKVR (win-token, 576), vectorized epilogue
  mfma_gemm<0><<<dim3(9, 512), 256, 0, stream>>>(SCR, QKVT, qkv_b, nullptr, QKVR,
                                                 576, 192, 192, 0, N_TOK, FLAG);
  // 3. MFMA windowed attention -> SCR (ATT)
  attn_mfma_kernel<<<dim3(6, 256), 256, 0, stream>>>(QKVR, relb, SCR, FLAG);
  // 4. proj + residual(x), window -> natural -> X1
  mfma_gemm<0><<<dim3(3, 512), 256, 0, stream>>>(SCR, PROJT, proj_b, x, X1,
                                                 192, 192, 192, 3, N_TOK, FLAG);
  // 5. LN2 -> SCR (H2)
  ln_kernel<<<N_TOK / 4, 256, 0, stream>>>(X1, n2g, n2b, SCR, 0, 1, FLAG);
  // 6. FC1: (N,192)@(192,768)+b -> F1 (f16, mode 5), vectorized epilogue
  mfma_gemm<0><<<dim3(12, 512), 256, 0, stream>>>(SCR, W1T, fc1_Bb, nullptr, F1,
                                                  768, 192, 192, 5, N_TOK, FLAG);
  // 7. depthwise conv + GELU, packed f16, d-sliding threads -> F2 (f16)
  dwconv_f16_kernel<<<6144, 256, 0, stream>>>(F1, DWT, dw_b, F2, FLAG);
  // 8. FC2 (f16 MFMA): (N,768)@(768,192)+b + residual(X1) -> out
  mfma_gemm<1><<<dim3(3, 512), 256, 0, stream>>>((const bf16*)F2, (const bf16*)W2T,
                                                 fc2_Bb, X1, d_out,
                                                 192, 768, 768, 1, N_TOK, FLAG);
}

// Round 16
// 609.569 us; speedup vs baseline: 1.0615x; 1.0615x over previous
//
#include <hip/hip_runtime.h>
#include <hip/hip_bf16.h>
#include <hip/hip_fp16.h>

typedef __hip_bfloat16 bf16;
typedef __attribute__((ext_vector_type(8))) short short8;
typedef __attribute__((ext_vector_type(8))) _Float16 half8;
typedef __attribute__((ext_vector_type(4))) float f32x4;

#define N_TOK 65536
#define C_DIM 192
#define SCALE 0.17677669529663687f

__device__ __forceinline__ float b2f(bf16 v) { return __bfloat162float(v); }
__device__ __forceinline__ bf16 f2b(float v) { return __float2bfloat16(v); }
__device__ __forceinline__ float ldA(const void* p, size_t i, int f32) {
  return f32 ? ((const float*)p)[i] : b2f(((const bf16*)p)[i]);
}
__device__ __forceinline__ float s2f(short s) { union { short s; bf16 b; } u; u.s = s; return b2f(u.b); }

// fast GELU (tanh form): s * sigmoid(1.5957691*s + 0.0713548*s^3); max err ~1e-3.
__device__ __forceinline__ float gelu_f(float s) {
  float t = s * s;
  float b = s * (-1.59576912f - 0.0713548162f * t);
  float e = __expf(b);
  return s / (1.f + e);
}

// ---------------- dtype detector (silent) ----------------
__global__ void detect_kernel(const unsigned short* __restrict__ xh, int* __restrict__ flag) {
  if (threadIdx.x == 0) {
    int crazy = 0;
    for (int i = 0; i < 256; ++i) {
      int e = (xh[i] >> 7) & 0xFF;
      if (e >= 0xF0 || (e >= 1 && e <= 0x60)) ++crazy;
    }
    *flag = (crazy >= 16) ? 1 : 0;
  }
}

// ---------------- prep: transposes + casts (all elementwise, exact 256-multiples) ------
__global__ __launch_bounds__(256) void prep_xpose_kernel(
    const void* __restrict__ qkv_w, bf16* __restrict__ QKVT,
    const void* __restrict__ proj_w, bf16* __restrict__ PROJT,
    const void* __restrict__ dw_w, _Float16* __restrict__ DWT,
    const void* __restrict__ fc1_A, bf16* __restrict__ FC1AB,
    const void* __restrict__ fc1_Bw, bf16* __restrict__ FC1BWT,
    const void* __restrict__ fc2_A, bf16* __restrict__ FC2AB,
    const void* __restrict__ fc2_Bw, bf16* __restrict__ FC2BWT,
    const int* __restrict__ flag) {
  int f32 = *flag;
  int b = blockIdx.x;
  if (b < 432) {
    int idx = b * 256 + threadIdx.x;
    int n = idx / 192, k = idx - n * 192;
    QKVT[idx] = f2b(ldA(qkv_w, (size_t)k * 576 + n, f32));
  } else if (b < 576) {
    int idx = (b - 432) * 256 + threadIdx.x;
    int n = idx / 192, k = idx - n * 192;
    PROJT[idx] = f2b(ldA(proj_w, (size_t)k * 192 + n, f32));
  } else if (b < 657) {
    int idx = (b - 576) * 256 + threadIdx.x;       // 27*768 exact
    int tap = idx / 768, c = idx - tap * 768;
    DWT[idx] = (_Float16)ldA(dw_w, (size_t)c * 27 + tap, f32);
  } else if (b < 945) {
    int idx = (b - 657) * 256 + threadIdx.x;       // 73728 exact
    FC1AB[idx] = f2b(ldA(fc1_A, idx, f32));
  } else if (b < 2097) {
    int idx = (b - 945) * 256 + threadIdx.x;       // 294912 exact
    int n = idx / 384, r = idx - n * 384;
    FC1BWT[idx] = f2b(ldA(fc1_Bw, (size_t)r * 768 + n, f32));
  } else if (b < 2385) {
    int idx = (b - 2097) * 256 + threadIdx.x;      // 73728 exact
    FC2AB[idx] = f2b(ldA(fc2_A, idx, f32));
  } else {
    int idx = (b - 2385) * 256 + threadIdx.x;      // 18432 exact
    int n = idx / 96, r = idx - n * 96;
    FC2BWT[idx] = f2b(ldA(fc2_Bw, (size_t)r * 192 + n, f32));
  }
}

// ---------------- LayerNorm ----------------
__global__ __launch_bounds__(256) void ln_kernel(const void* __restrict__ x,
    const void* __restrict__ g, const void* __restrict__ b, bf16* __restrict__ out,
    int windowize, int xIsBf16Fixed, const int* __restrict__ flag) {
  int wf32 = *flag;
  int f32 = xIsBf16Fixed ? 0 : wf32;
  int token = blockIdx.x * 4 + (threadIdx.x >> 6);
  int lane = threadIdx.x & 63;
  size_t base = (size_t)token * C_DIM;
  float v0 = ldA(x, base + lane, f32);
  float v1 = ldA(x, base + lane + 64, f32);
  float v2 = ldA(x, base + lane + 128, f32);
  float s = v0 + v1 + v2;
  float s2 = v0 * v0 + v1 * v1 + v2 * v2;
  #pragma unroll
  for (int o = 32; o > 0; o >>= 1) { s += __shfl_xor(s, o, 64); s2 += __shfl_xor(s2, o, 64); }
  float mu = s * (1.f / 192.f);
  float var = s2 * (1.f / 192.f) - mu * mu;
  float rstd = rsqrtf(var + 1e-5f);
  int row = token;
  if (windowize) {
    int d = token >> 12, h = (token >> 6) & 63, w = token & 63;
    int win = ((d >> 2) << 6) + ((h >> 3) << 3) + (w >> 3);
    int t = ((d & 3) << 6) + ((h & 7) << 3) + (w & 7);
    row = win * 256 + t;
  }
  bf16* po = out + (size_t)row * C_DIM;
  po[lane]       = f2b((v0 - mu) * rstd * ldA(g, lane, wf32)       + ldA(b, lane, wf32));
  po[lane + 64]  = f2b((v1 - mu) * rstd * ldA(g, lane + 64, wf32)  + ldA(b, lane + 64, wf32));
  po[lane + 128] = f2b((v2 - mu) * rstd * ldA(g, lane + 128, wf32) + ldA(b, lane + 128, wf32));
}

// ---------------- MFMA GEMM, BK=96, global_load_lds staging (linear LDS) ----------------
// Template F16: 0 = bf16 MFMA inputs, 1 = f16 MFMA inputs.
// mode 0: bf16 store (+bias); 1: adaptive + residual(bf16); 3: window->natural + res(adaptive);
// 4: transposed bf16 store; 5: f16 store (+bias); 6: transposed f16 store.
// Modes 0/5: LDS-staged 16B store epilogue (R14, verified).
// Modes 1/3: f32 LDS staging in two 64-row halves + vectorized res-load/add/store.
template<int F16>
__global__ __launch_bounds__(256) void mfma_gemm(const bf16* __restrict__ A,
    const bf16* __restrict__ BT, const void* __restrict__ bias,
    const void* __restrict__ res, void* __restrict__ out,
    int Nc, int K, int ldk, int mode, int Mrows, const int* __restrict__ flag) {
  int f32 = *flag;
  __shared__ short As[128 * 96];
  __shared__ short Bs[64 * 96];
  int tid = threadIdx.x;
  int wave = tid >> 6, lane = tid & 63;
  int wm = wave >> 1, wn = wave & 1;
  int lr = lane & 15, quad = lane >> 4;
  int rowBase, colBase;
  if (gridDim.y >= 8) {
    int ncb = gridDim.x;
    int flat = blockIdx.x + ncb * blockIdx.y;
    int group = flat / (8 * ncb);
    int r = flat - group * 8 * ncb;
    rowBase = (group * 8 + (r & 7)) * 128;
    colBase = (r >> 3) * 64;
  } else {
    rowBase = blockIdx.y * 128;
    colBase = blockIdx.x * 64;
  }
  f32x4 acc[4][2];
  #pragma unroll
  for (int i = 0; i < 4; ++i)
    #pragma unroll
    for (int j = 0; j < 2; ++j) acc[i][j] = f32x4{0.f, 0.f, 0.f, 0.f};

  const bf16* arow = A + (size_t)rowBase * K;
  const bf16* brow = BT + (size_t)colBase * ldk;

  for (int k0 = 0; k0 < K; k0 += 96) {
    #pragma unroll
    for (int it = 0; it < 6; ++it) {
      int u = tid + it * 256;
      int row = u / 12, kc = (u - row * 12) * 8;
      __builtin_amdgcn_global_load_lds(
          (const __attribute__((address_space(1))) void*)(arow + (size_t)row * K + k0 + kc),
          (__attribute__((address_space(3))) void*)&As[u * 8], 16, 0, 0);
    }
    #pragma unroll
    for (int it = 0; it < 3; ++it) {
      int u = tid + it * 256;
      int n = u / 12, kc = (u - n * 12) * 8;
      __builtin_amdgcn_global_load_lds(
          (const __attribute__((address_space(1))) void*)(brow + (size_t)n * ldk + k0 + kc),
          (__attribute__((address_space(3))) void*)&Bs[u * 8], 16, 0, 0);
    }
    __syncthreads();
    #pragma unroll
    for (int kk = 0; kk < 3; ++kk) {
      short8 af[4], bf[2];
      #pragma unroll
      for (int i = 0; i < 4; ++i)
        af[i] = *(const short8*)&As[(wm * 64 + i * 16 + lr) * 96 + kk * 32 + quad * 8];
      #pragma unroll
      for (int j = 0; j < 2; ++j)
        bf[j] = *(const short8*)&Bs[(wn * 32 + j * 16 + lr) * 96 + kk * 32 + quad * 8];
      #pragma unroll
      for (int i = 0; i < 4; ++i)
        #pragma unroll
        for (int j = 0; j < 2; ++j) {
          if constexpr (F16) {
            union { short8 s; half8 h; } ua, ub;
            ua.s = af[i]; ub.s = bf[j];
            acc[i][j] = __builtin_amdgcn_mfma_f32_16x16x32_f16(ua.h, ub.h, acc[i][j], 0, 0, 0);
          } else {
            acc[i][j] = __builtin_amdgcn_mfma_f32_16x16x32_bf16(af[i], bf[j], acc[i][j], 0, 0, 0);
          }
        }
    }
    __syncthreads();
  }

  if (mode == 0 || mode == 5) {
    // ---- vectorized epilogue: stage C tile in LDS, then 16B coalesced stores ----
    short* Cs = As;                         // 128 x 72 shorts = 18.4 KB, free now
    #pragma unroll
    for (int i = 0; i < 4; ++i) {
      #pragma unroll
      for (int j = 0; j < 2; ++j) {
        #pragma unroll
        for (int r4 = 0; r4 < 4; ++r4) {
          int row = wm * 64 + i * 16 + quad * 4 + r4;
          int c = wn * 32 + j * 16 + lr;
          float v = acc[i][j][r4];
          if (bias) v += ldA(bias, colBase + c, f32);
          short bits;
          if (mode == 5) { union { _Float16 h; short s; } u2; u2.h = (_Float16)v; bits = u2.s; }
          else           { union { bf16 b; short s; } u2; u2.b = f2b(v); bits = u2.s; }
          Cs[row * 72 + c] = bits;
        }
      }
    }
    __syncthreads();
    int row = tid >> 1, half = tid & 1;     // 2 threads/row, 32 shorts each
    size_t gbase = (size_t)(rowBase + row) * Nc + colBase + half * 32;
    #pragma unroll
    for (int ch = 0; ch < 4; ++ch) {
      short8 vv = *(const short8*)&Cs[row * 72 + half * 32 + ch * 8];
      if (mode == 5) *(short8*)((_Float16*)out + gbase + ch * 8) = vv;
      else           *(short8*)((bf16*)out + gbase + ch * 8) = vv;
    }
    return;
  }

  if (mode == 1 || mode == 3) {
    // ---- f32-staged vectorized residual epilogue, two 64-row halves ----
    float* Fs = (float*)As;                 // 64 x 68 floats (272B rows, 16B-aligned) = 17.4 KB
    #pragma unroll
    for (int p = 0; p < 2; ++p) {
      if (wm == p) {
        #pragma unroll
        for (int i = 0; i < 4; ++i)
          #pragma unroll
          for (int j = 0; j < 2; ++j)
            #pragma unroll
            for (int r4 = 0; r4 < 4; ++r4) {
              int row = i * 16 + quad * 4 + r4;          // 0..63 within half
              int c = wn * 32 + j * 16 + lr;
              float v = acc[i][j][r4];
              if (bias) v += ldA(bias, colBase + c, f32);
              Fs[row * 68 + c] = v;
            }
      }
      __syncthreads();
      int row = tid >> 2, qt = tid & 3;     // 4 threads/row, 16 floats each
      int grow = rowBase + p * 64 + row;
      int n = grow;
      if (mode == 3) {
        int win = grow >> 8, t = grow & 255;
        int d = ((win >> 6) << 2) + (t >> 6);
        int h = (((win >> 3) & 7) << 3) + ((t >> 3) & 7);
        int w = ((win & 7) << 3) + (t & 7);
        n = (d << 12) + (h << 6) + w;
      }
      size_t gb = (size_t)n * Nc + colBase + qt * 16;
      float vals[16];
      #pragma unroll
      for (int e2 = 0; e2 < 4; ++e2) {
        f32x4 fv = *(const f32x4*)&Fs[row * 68 + qt * 16 + e2 * 4];
        vals[e2 * 4] = fv[0]; vals[e2 * 4 + 1] = fv[1];
        vals[e2 * 4 + 2] = fv[2]; vals[e2 * 4 + 3] = fv[3];
      }
      if (mode == 3) {
        // res = x (adaptive), out = X1 bf16
        if (f32) {
          #pragma unroll
          for (int e2 = 0; e2 < 4; ++e2) {
            f32x4 rv = *(const f32x4*)((const float*)res + gb + e2 * 4);
            #pragma unroll
            for (int e = 0; e < 4; ++e) vals[e2 * 4 + e] += rv[e];
          }
        } else {
          #pragma unroll
          for (int e2 = 0; e2 < 2; ++e2) {
            short8 rv = *(const short8*)((const bf16*)res + gb + e2 * 8);
            #pragma unroll
            for (int e = 0; e < 8; ++e) vals[e2 * 8 + e] += s2f(rv[e]);
          }
        }
        short8 o0, o1;
        #pragma unroll
        for (int e = 0; e < 8; ++e) {
          union { bf16 b; short s; } u0, u1;
          u0.b = f2b(vals[e]); u1.b = f2b(vals[8 + e]);
          o0[e] = u0.s; o1[e] = u1.s;
        }
        *(short8*)((bf16*)out + gb) = o0;
        *(short8*)((bf16*)out + gb + 8) = o1;
      } else {
        // mode 1: res = X1 bf16, out adaptive (final)
        #pragma unroll
        for (int e2 = 0; e2 < 2; ++e2) {
          short8 rv = *(const short8*)((const bf16*)res + gb + e2 * 8);
          #pragma unroll
          for (int e = 0; e < 8; ++e) vals[e2 * 8 + e] += s2f(rv[e]);
        }
        if (f32) {
          #pragma unroll
          for (int e2 = 0; e2 < 4; ++e2) {
            f32x4 ov;
            ov[0] = vals[e2 * 4]; ov[1] = vals[e2 * 4 + 1];
            ov[2] = vals[e2 * 4 + 2]; ov[3] = vals[e2 * 4 + 3];
            *(f32x4*)((float*)out + gb + e2 * 4) = ov;
          }
        } else {
          short8 o0, o1;
          #pragma unroll
          for (int e = 0; e < 8; ++e) {
            union { bf16 b; short s; } u0, u1;
            u0.b = f2b(vals[e]); u1.b = f2b(vals[8 + e]);
            o0[e] = u0.s; o1[e] = u1.s;
          }
          *(short8*)((bf16*)out + gb) = o0;
          *(short8*)((bf16*)out + gb + 8) = o1;
        }
      }
      __syncthreads();   // before next half reuses Fs
    }
    return;
  }

  // ---- scalar path (modes 4/6: small weight GEMMs) ----
  #pragma unroll
  for (int i = 0; i < 4; ++i) {
    #pragma unroll
    for (int j = 0; j < 2; ++j) {
      #pragma unroll
      for (int r4 = 0; r4 < 4; ++r4) {
        int row = rowBase + wm * 64 + i * 16 + quad * 4 + r4;
        int c = colBase + wn * 32 + j * 16 + lr;
        if (c >= Nc || row >= Mrows) continue;
        float v = acc[i][j][r4];
        if (bias) v += ldA(bias, c, f32);
        if (mode == 4) {
          ((bf16*)out)[(size_t)c * Mrows + row] = f2b(v);
        } else if (mode == 6) {
          ((_Float16*)out)[(size_t)c * Mrows + row] = (_Float16)v;
        }
      }
    }
  }
}

// ---------------- MFMA attention from row-major QKV (win-token, 576) ----------------
__global__ __launch_bounds__(256) void attn_mfma_kernel(const bf16* __restrict__ qkvr,
    const void* __restrict__ rel_bias, bf16* __restrict__ out,
    const int* __restrict__ flag) {
  int f32 = *flag;
  __shared__ bf16 sK[256 * 40];
  __shared__ bf16 sVT[32 * 264];
  __shared__ bf16 sP[4][64 * 40];
  __shared__ float sb[1575];
  __shared__ int  sgb[256];
  int head = blockIdx.x, win = blockIdx.y;
  const bf16* base = qkvr + (size_t)win * 256 * 576;
  int qoff = head * 32, koff = 192 + head * 32, voff = 384 + head * 32;
  int tid = threadIdx.x;
  int wave = tid >> 6, lane = tid & 63;
  int lr = lane & 15, quad = lane >> 4;

  #pragma unroll
  for (int it = 0; it < 4; ++it) {
    int idx = tid + it * 256;              // 0..1023
    int tok = idx >> 2, kc = (idx & 3) * 8;
    uint4 v = *(const uint4*)(base + (size_t)tok * 576 + koff + kc);
    *(uint4*)&sK[tok * 40 + kc] = v;
  }
  for (int idx = tid; idx < 8192; idx += 256) {
    int tok = idx >> 5, hd = idx & 31;
    sVT[hd * 264 + tok] = base[(size_t)tok * 576 + voff + hd];
  }
  for (int idx = tid; idx < 1575; idx += 256) sb[idx] = ldA(rel_bias, (size_t)idx * 6 + head, f32);
  {
    int t = tid & 255;
    int d = ((win >> 6) << 2) + (t >> 6);
    int h = (((win >> 3) & 7) << 3) + ((t >> 3) & 7);
    int w = ((win & 7) << 3) + (t & 7);
    int d2 = (d + 2) & 15, h2 = (h + 4) & 63, w2 = (w + 4) & 63;
    int g = ((d2 >> 2) << 6) + ((h2 >> 3) << 3) + (w2 >> 3);
    int td = t >> 6, th = (t >> 3) & 7, tw = t & 7;
    int bse = (td * 15 + th) * 15 + tw;
    sgb[t] = (g << 12) | bse;
  }
  __syncthreads();

  int wm = wave * 64;
  short8 aq[4];
  #pragma unroll
  for (int i = 0; i < 4; ++i)
    aq[i] = *(const short8*)(base + (size_t)(wm + i * 16 + lr) * 576 + qoff + quad * 8);
  int rinfo[16];
  #pragma unroll
  for (int i = 0; i < 4; ++i)
    #pragma unroll
    for (int r = 0; r < 4; ++r)
      rinfo[i * 4 + r] = sgb[wm + i * 16 + quad * 4 + r];

  f32x4 acc_o[4][2], acc_l[4];
  #pragma unroll
  for (int i = 0; i < 4; ++i) {
    acc_l[i] = f32x4{0.f, 0.f, 0.f, 0.f};
    #pragma unroll
    for (int j = 0; j < 2; ++j) acc_o[i][j] = f32x4{0.f, 0.f, 0.f, 0.f};
  }
  short8 bones;
  #pragma unroll
  for (int j = 0; j < 8; ++j) bones[j] = (lr == 0) ? (short)0x3F80 : (short)0;

  for (int c = 0; c < 8; ++c) {
    short8 bk[2];
    #pragma unroll
    for (int jt = 0; jt < 2; ++jt)
      bk[jt] = *(const short8*)&sK[(c * 32 + jt * 16 + lr) * 40 + quad * 8];
    f32x4 s[4][2];
    #pragma unroll
    for (int i = 0; i < 4; ++i)
      #pragma unroll
      for (int jt = 0; jt < 2; ++jt) {
        s[i][jt] = f32x4{0.f, 0.f, 0.f, 0.f};
        s[i][jt] = __builtin_amdgcn_mfma_f32_16x16x32_bf16(aq[i], bk[jt], s[i][jt], 0, 0, 0);
      }
    int cinfo[2];
    #pragma unroll
    for (int jt = 0; jt < 2; ++jt) cinfo[jt] = sgb[c * 32 + jt * 16 + lr];
    #pragma unroll
    for (int i = 0; i < 4; ++i)
      #pragma unroll
      for (int jt = 0; jt < 2; ++jt)
        #pragma unroll
        for (int r = 0; r < 4; ++r) {
          int ri = rinfo[i * 4 + r], ci = cinfo[jt];
          float sc = s[i][jt][r] * SCALE + sb[(ri & 0xFFF) - (ci & 0xFFF) + 787];
          float p = ((ri >> 12) == (ci >> 12)) ? __expf(sc) : 0.f;
          sP[wave][(i * 16 + quad * 4 + r) * 40 + jt * 16 + lr] = f2b(p);
        }
    short8 ap[4];
    #pragma unroll
    for (int i = 0; i < 4; ++i)
      ap[i] = *(const short8*)&sP[wave][(i * 16 + lr) * 40 + quad * 8];
    short8 bv[2];
    #pragma unroll
    for (int jh = 0; jh < 2; ++jh)
      bv[jh] = *(const short8*)&sVT[(jh * 16 + lr) * 264 + c * 32 + quad * 8];
    #pragma unroll
    for (int i = 0; i < 4; ++i) {
      #pragma unroll
      for (int jh = 0; jh < 2; ++jh)
        acc_o[i][jh] = __builtin_amdgcn_mfma_f32_16x16x32_bf16(ap[i], bv[jh], acc_o[i][jh], 0, 0, 0);
      acc_l[i] = __builtin_amdgcn_mfma_f32_16x16x32_bf16(ap[i], bones, acc_l[i], 0, 0, 0);
    }
  }
  #pragma unroll
  for (int i = 0; i < 4; ++i) {
    #pragma unroll
    for (int r = 0; r < 4; ++r) {
      float l = __shfl(acc_l[i][r], lane & 48, 64);
      float inv = 1.f / l;
      int t = wm + i * 16 + quad * 4 + r;
      bf16* po = out + (size_t)(win * 256 + t) * C_DIM + head * 32;
      po[lr]      = f2b(acc_o[i][0][r] * inv);
      po[16 + lr] = f2b(acc_o[i][1][r] * inv);
    }
  }
}

// ---------------- Depthwise conv + GELU, packed f16 (8 ch x 4 tokens, sliding w) ------
// R14 configuration (best measured end-to-end): natural block order, f16 math.
// ~130 us is this kernel's floor across 3 mapping variants (R11/R12/R15).
__global__ __launch_bounds__(256, 8) void dwconv_f16_kernel(const _Float16* __restrict__ in,
    const _Float16* __restrict__ wT, const void* __restrict__ wb, _Float16* __restrict__ out,
    const int* __restrict__ flag) {
  int f32 = *flag;
  int idx = blockIdx.x * 256 + threadIdx.x;   // 16384 * 96
  int n4 = idx / 96, g = idx - n4 * 96;
  int c0 = g * 8;
  int d = n4 >> 10, h = (n4 >> 4) & 63, w0 = (n4 & 15) << 2;
  const _Float16* inb = in + c0;
  half8 acc[4];
  #pragma unroll
  for (int t = 0; t < 4; ++t)
    #pragma unroll
    for (int e = 0; e < 8; ++e) acc[t][e] = (_Float16)0.f;
  #pragma unroll
  for (int kd = 0; kd < 3; ++kd) {
    int dd = d + kd - 1;
    if ((unsigned)dd >= 16u) continue;
    #pragma unroll
    for (int kh = 0; kh < 3; ++kh) {
      int hh = h + kh - 1;
      if ((unsigned)hh >= 64u) continue;
      int rowbase = (dd << 12) + (hh << 6);
      half8 xf[6];
      #pragma unroll
      for (int j = 0; j < 6; ++j) {
        int ww = w0 + j - 1;
        if ((unsigned)ww < 64u) {
          xf[j] = *(const half8*)(inb + (size_t)(rowbase + ww) * 768);
        } else {
          #pragma unroll
          for (int e = 0; e < 8; ++e) xf[j][e] = (_Float16)0.f;
        }
      }
      #pragma unroll
      for (int kw = 0; kw < 3; ++kw) {
        int tap = kd * 9 + kh * 3 + kw;
        half8 wv = *(const half8*)(wT + tap * 768 + c0);
        #pragma unroll
        for (int t = 0; t < 4; ++t)
          acc[t] += xf[t + kw] * wv;        // v_pk_fma_f16 x4
      }
    }
  }
  float biasf[8];
  #pragma unroll
  for (int e = 0; e < 8; ++e) biasf[e] = ldA(wb, c0 + e, f32);
  #pragma unroll
  for (int t = 0; t < 4; ++t) {
    half8 po;
    #pragma unroll
    for (int e = 0; e < 8; ++e) {
      float s = (float)acc[t][e] + biasf[e];
      po[e] = (_Float16)gelu_f(s);
    }
    *(half8*)(out + (size_t)((d << 12) + (h << 6) + w0 + t) * 768 + c0) = po;
  }
}

extern "C" void kernel_launch(void* const* d_in, const int* in_sizes, int n_in,
                              void* d_out, int out_size, void* d_ws, size_t ws_size,
                              hipStream_t stream) {
  const void* x      = d_in[0];
  const void* n1g    = d_in[1];
  const void* n1b    = d_in[2];
  const void* qkv_w  = d_in[3];
  const void* qkv_b  = d_in[4];
  const void* relb   = d_in[5];
  const void* proj_w = d_in[6];
  const void* proj_b = d_in[7];
  const void* n2g    = d_in[8];
  const void* n2b    = d_in[9];
  const void* fc1_A  = d_in[10];
  const void* fc1_Bw = d_in[11];
  const void* fc1_Bb = d_in[12];
  const void* dw_w   = d_in[13];
  const void* dw_b   = d_in[14];
  const void* fc2_A  = d_in[15];
  const void* fc2_Bw = d_in[16];
  const void* fc2_Bb = d_in[17];

  // ws layout (MiB), 256 total.
  char* ws = (char*)d_ws;
  bf16* SCR  = (bf16*)d_out;                         // H1 / ATT / H2 scratch
  bf16* X1   = (bf16*)(ws);
  bf16* QKVR = (bf16*)(ws + (size_t)24 * 1048576);
  _Float16* F2 = (_Float16*)(ws + (size_t)24 * 1048576);
  _Float16* F1 = (_Float16*)(ws + (size_t)120 * 1048576);
  bf16* QKVT   = (bf16*)(ws + (size_t)228 * 1048576); // (576,192)
  bf16* PROJT  = (bf16*)(ws + (size_t)229 * 1048576); // (192,192)
  _Float16* DWT = (_Float16*)(ws + (size_t)230 * 1048576); // (27,768) f16
  bf16* W1T    = (bf16*)(ws + (size_t)231 * 1048576); // (768,192) bf16
  _Float16* W2T = (_Float16*)(ws + (size_t)232 * 1048576); // (192,768) f16
  bf16* FC1AB  = (bf16*)(ws + (size_t)233 * 1048576); // (192,384) bf16 cast
  bf16* FC1BWT = (bf16*)(ws + (size_t)234 * 1048576); // (768,384) transpose
  bf16* FC2AB  = (bf16*)(ws + (size_t)236 * 1048576); // (768,96) bf16 cast
  bf16* FC2BWT = (bf16*)(ws + (size_t)237 * 1048576); // (192,96) transpose
  int* FLAG    = (int*)(ws + (size_t)255 * 1048576);

  // 0. dtype detect + weight prep
  detect_kernel<<<1, 64, 0, stream>>>((const unsigned short*)x, FLAG);
  prep_xpose_kernel<<<2457, 256, 0, stream>>>(qkv_w, QKVT, proj_w, PROJT, dw_w, DWT,
                                              fc1_A, FC1AB, fc1_Bw, FC1BWT,
                                              fc2_A, FC2AB, fc2_Bw, FC2BWT, FLAG);
  // 0b. W1 = fc1_A @ fc1_Bw (192x768, K=384) -> W1T bf16, mode 4 transposed store
  mfma_gemm<0><<<dim3(12, 2), 256, 0, stream>>>(FC1AB, FC1BWT, nullptr, nullptr, W1T,
                                                768, 384, 384, 4, 192, FLAG);
  // 0c. W2 = fc2_A @ fc2_Bw (768x192, K=96) -> W2T f16, mode 6
  mfma_gemm<0><<<dim3(3, 6), 256, 0, stream>>>(FC2AB, FC2BWT, nullptr, nullptr, W2T,
                                               192, 96, 96, 6, 768, FLAG);
  // 1. LN1 + window gather -> SCR (H1)
  ln_kernel<<<N_TOK / 4, 256, 0, stream>>>(x, n1g, n1b, SCR, 1, 0, FLAG);
  // 2. QKV gemm -> row-major QKVR (win-token, 576), vectorized epilogue
  mfma_gemm<0><<<dim3(9, 512), 256, 0, stream>>>(SCR, QKVT, qkv_b, nullptr, QKVR,
                                                 576, 192, 192, 0, N_TOK, FLAG);
  // 3. MFMA windowed attention -> SCR (ATT)
  attn_mfma_kernel<<<dim3(6, 256), 256, 0, stream>>>(QKVR, relb, SCR, FLAG);
  // 4. proj + residual(x), window -> natural -> X1 (vectorized res epilogue)
  mfma_gemm<0><<<dim3(3, 512), 256, 0, stream>>>(SCR, PROJT, proj_b, x, X1,
                                                 192, 192, 192, 3, N_TOK, FLAG);
  // 5. LN2 -> SCR (H2)
  ln_kernel<<<N_TOK / 4, 256, 0, stream>>>(X1, n2g, n2b, SCR, 0, 1, FLAG);
  // 6. FC1: (N,192)@(192,768)+b -> F1 (f16, mode 5), vectorized epilogue
  mfma_gemm<0><<<dim3(12, 512), 256, 0, stream>>>(SCR, W1T, fc1_Bb, nullptr, F1,
                                                  768, 192, 192, 5, N_TOK, FLAG);
  // 7. depthwise conv + GELU, packed f16 -> F2 (f16)
  dwconv_f16_kernel<<<6144, 256, 0, stream>>>(F1, DWT, dw_b, F2, FLAG);
  // 8. FC2 (f16 MFMA): (N,768)@(768,192)+b + residual(X1) -> out (vectorized res epilogue)
  mfma_gemm<1><<<dim3(3, 512), 256, 0, stream>>>((const bf16*)F2, (const bf16*)W2T,
                                                 fc2_Bb, X1, d_out,
                                                 192, 768, 768, 1, N_TOK, FLAG);
}